// Round 8
// baseline (157.205 us; speedup 1.0000x reference)
//
#include <hip/hip_runtime.h>
#include <hip/hip_bf16.h>

#define S_LEN 4096
#define NEG_INF_F (-1e30f)

typedef __attribute__((ext_vector_type(4))) float f32x4;
typedef __attribute__((ext_vector_type(8))) short s16x8;
typedef unsigned short u16;

static __device__ __forceinline__ u16 f2bf(float f) {
    unsigned u = __builtin_bit_cast(unsigned, f);
    unsigned r = u + 0x7FFFu + ((u >> 16) & 1u);
    return (u16)(r >> 16);
}
static __device__ __forceinline__ float bf2f(u16 h) {
    unsigned u = ((unsigned)h) << 16;
    return __builtin_bit_cast(float, u);
}
static __device__ __forceinline__ void split4(const float4 v, ushort4& hi, ushort4& lo) {
    hi.x = f2bf(v.x); lo.x = f2bf(v.x - bf2f(hi.x));
    hi.y = f2bf(v.y); lo.y = f2bf(v.y - bf2f(hi.y));
    hi.z = f2bf(v.z); lo.z = f2bf(v.z - bf2f(hi.z));
    hi.w = f2bf(v.w); lo.w = f2bf(v.w - bf2f(hi.w));
}
static __device__ __forceinline__ void gl_lds16(const void* g, void* l) {
    __builtin_amdgcn_global_load_lds(
        (const __attribute__((address_space(1))) void*)g,
        (__attribute__((address_space(3))) void*)l, 16, 0, 0);
}
// swizzled u16 offset within a [rows][64 u16] LDS tile
static __device__ __forceinline__ int swz64(int row, int col_u16) {
    return row * 64 + (col_u16 ^ ((row & 7) << 3));
}
// swizzled u16 offset within a [rows][320 u16] LDS tile (XOR within octet group)
static __device__ __forceinline__ int swz320(int row, int col_u16) {
    return row * 320 + (col_u16 ^ ((row & 7) << 3));
}
// XCD-chunked bijective swizzle for nwg=512
static __device__ __forceinline__ int xcd_swz512(int bid) {
    return (bid & 7) * 64 + (bid >> 3);
}

// ---------------- K0: split x -> xh, xl AND xT (fused transpose) ----------------
__global__ __launch_bounds__(256) void split_xt_kernel(
    const float* __restrict__ x, u16* __restrict__ xh, u16* __restrict__ xl,
    u16* __restrict__ xT) {
    const int bid = blockIdx.x;
    const int dt = bid & 7, st = (bid >> 3) & 63, b = bid >> 9;
    const int s0 = st * 64, d0 = dt * 64;
    __shared__ u16 T[64][72];
    const int tid = threadIdx.x;
    #pragma unroll
    for (int i = 0; i < 4; ++i) {
        int idx = i * 256 + tid;
        int r = idx >> 4, c4 = (idx & 15) * 4;
        float4 v = *(const float4*)(x + (size_t)(b * S_LEN + s0 + r) * 512 + d0 + c4);
        ushort4 hi, lo; split4(v, hi, lo);
        *(ushort4*)(xh + (size_t)(b * S_LEN + s0 + r) * 512 + d0 + c4) = hi;
        *(ushort4*)(xl + (size_t)(b * S_LEN + s0 + r) * 512 + d0 + c4) = lo;
        *(ushort4*)&T[r][c4] = hi;
    }
    __syncthreads();
    #pragma unroll
    for (int i = 0; i < 2; ++i) {
        int idx = i * 256 + tid;
        int dr = idx >> 3, sc = idx & 7;
        s16x8 v;
        #pragma unroll
        for (int t = 0; t < 8; ++t) v[t] = (short)T[sc * 8 + t][dr];
        *(s16x8*)&xT[(size_t)(b * 512 + d0 + dr) * S_LEN + s0 + sc * 8] = v;
    }
}

// ---------------- K1: Mt = Wk^T @ Wq ----------------
__global__ __launch_bounds__(256) void mt_kernel(
    const float* __restrict__ Wk, const float* __restrict__ Wq,
    u16* __restrict__ Mth, u16* __restrict__ Mtl) {
    const int bm = blockIdx.x & 7, bn = blockIdx.x >> 3;
    const int m0 = bm * 64, n0 = bn * 64;
    __shared__ __align__(16) u16 Ath[64 * 72], Atl[64 * 72];
    __shared__ __align__(16) u16 Bth[64 * 72], Btl[64 * 72];
    const int tid = threadIdx.x, lane = tid & 63, w = tid >> 6;
    const int frow = lane & 15, fk = (lane >> 4) * 8;
    f32x4 acc[4] = {};

    for (int h0 = 0; h0 < 512; h0 += 64) {
        #pragma unroll
        for (int i = 0; i < 4; ++i) {
            int idx = i * 256 + tid;
            int h = idx >> 4, c4 = (idx & 15) * 4;
            float4 a = *(const float4*)(Wk + (size_t)(h0 + h) * 512 + m0 + c4);
            ushort4 ahi, alo; split4(a, ahi, alo);
            Ath[(c4 + 0) * 72 + h] = ahi.x; Atl[(c4 + 0) * 72 + h] = alo.x;
            Ath[(c4 + 1) * 72 + h] = ahi.y; Atl[(c4 + 1) * 72 + h] = alo.y;
            Ath[(c4 + 2) * 72 + h] = ahi.z; Atl[(c4 + 2) * 72 + h] = alo.z;
            Ath[(c4 + 3) * 72 + h] = ahi.w; Atl[(c4 + 3) * 72 + h] = alo.w;
            float4 b = *(const float4*)(Wq + (size_t)(h0 + h) * 512 + n0 + c4);
            ushort4 bhi, blo; split4(b, bhi, blo);
            Bth[(c4 + 0) * 72 + h] = bhi.x; Btl[(c4 + 0) * 72 + h] = blo.x;
            Bth[(c4 + 1) * 72 + h] = bhi.y; Btl[(c4 + 1) * 72 + h] = blo.y;
            Bth[(c4 + 2) * 72 + h] = bhi.z; Btl[(c4 + 2) * 72 + h] = blo.z;
            Bth[(c4 + 3) * 72 + h] = bhi.w; Btl[(c4 + 3) * 72 + h] = blo.w;
        }
        __syncthreads();
        #pragma unroll
        for (int kk = 0; kk < 2; ++kk) {
            s16x8 aH = *(const s16x8*)&Ath[(w * 16 + frow) * 72 + kk * 32 + fk];
            s16x8 aL = *(const s16x8*)&Atl[(w * 16 + frow) * 72 + kk * 32 + fk];
            #pragma unroll
            for (int ni = 0; ni < 4; ++ni) {
                s16x8 bH = *(const s16x8*)&Bth[(ni * 16 + frow) * 72 + kk * 32 + fk];
                s16x8 bL = *(const s16x8*)&Btl[(ni * 16 + frow) * 72 + kk * 32 + fk];
                acc[ni] = __builtin_amdgcn_mfma_f32_16x16x32_bf16(aH, bH, acc[ni], 0, 0, 0);
                acc[ni] = __builtin_amdgcn_mfma_f32_16x16x32_bf16(aH, bL, acc[ni], 0, 0, 0);
                acc[ni] = __builtin_amdgcn_mfma_f32_16x16x32_bf16(aL, bH, acc[ni], 0, 0, 0);
            }
        }
        __syncthreads();
    }
    #pragma unroll
    for (int ni = 0; ni < 4; ++ni) {
        int d1 = n0 + ni * 16 + frow;
        #pragma unroll
        for (int e = 0; e < 4; ++e) {
            int d2 = m0 + w * 16 + (lane >> 4) * 4 + e;
            float v = acc[ni][e];
            u16 hi = f2bf(v);
            Mth[(size_t)d2 * 512 + d1] = hi;
            Mtl[(size_t)d2 * 512 + d1] = f2bf(v - bf2f(hi));
        }
    }
}

// ---------------- K2: u = Wk^T @ bq ----------------
__global__ __launch_bounds__(256) void u_kernel(
    const float* __restrict__ Wk, const float* __restrict__ bq,
    float* __restrict__ u) {
    __shared__ float red[4][64];
    const int tid = threadIdx.x, c = tid & 63, hg = tid >> 6;
    const int d2 = blockIdx.x * 64 + c;
    float acc = 0.f;
    for (int h = hg; h < 512; h += 4) acc += Wk[(size_t)h * 512 + d2] * bq[h];
    red[hg][c] = acc;
    __syncthreads();
    if (hg == 0) u[d2] = red[0][c] + red[1][c] + red[2][c] + red[3][c];
}

// ---------------- K3: z = x @ Mt^T + u ----------------
__global__ __launch_bounds__(512) void z_kernel(
    const u16* __restrict__ xh, const u16* __restrict__ xl,
    const u16* __restrict__ Mth, const u16* __restrict__ Mtl,
    const float* __restrict__ u, u16* __restrict__ zh, u16* __restrict__ zl) {
    const int w_ = xcd_swz512((int)blockIdx.x);
    const int bm = w_ >> 2, bn = w_ & 3;
    const int m0 = bm * 128, n0 = bn * 128;
    __shared__ __align__(16) u16 Ah[128 * 64], Al[128 * 64];
    __shared__ __align__(16) u16 Bh[128 * 64], Bl[128 * 64];
    const int tid = threadIdx.x, lane = tid & 63, w = tid >> 6;
    const int rg = w >> 2, cg = w & 3;
    const int frow = lane & 15, fk = (lane >> 4) * 8;
    f32x4 acc[4][2] = {};

    for (int k0 = 0; k0 < 512; k0 += 64) {
        #pragma unroll
        for (int i = 0; i < 2; ++i) {
            int idx = i * 512 + tid;
            int r = idx >> 3, c = idx & 7;
            int sc = (c ^ (r & 7)) * 8;
            gl_lds16(xh + (size_t)(m0 + r) * 512 + k0 + sc, &Ah[idx * 8]);
            gl_lds16(xl + (size_t)(m0 + r) * 512 + k0 + sc, &Al[idx * 8]);
            gl_lds16(Mth + (size_t)(n0 + r) * 512 + k0 + sc, &Bh[idx * 8]);
            gl_lds16(Mtl + (size_t)(n0 + r) * 512 + k0 + sc, &Bl[idx * 8]);
        }
        __syncthreads();
        #pragma unroll
        for (int kk = 0; kk < 2; ++kk) {
            s16x8 aH[4], aL[4], bH[2], bL[2];
            #pragma unroll
            for (int mi = 0; mi < 4; ++mi) {
                int row = rg * 64 + mi * 16 + frow;
                aH[mi] = *(const s16x8*)&Ah[swz64(row, kk * 32 + fk)];
                aL[mi] = *(const s16x8*)&Al[swz64(row, kk * 32 + fk)];
            }
            #pragma unroll
            for (int ni = 0; ni < 2; ++ni) {
                int row = cg * 32 + ni * 16 + frow;
                bH[ni] = *(const s16x8*)&Bh[swz64(row, kk * 32 + fk)];
                bL[ni] = *(const s16x8*)&Bl[swz64(row, kk * 32 + fk)];
            }
            #pragma unroll
            for (int mi = 0; mi < 4; ++mi)
                #pragma unroll
                for (int ni = 0; ni < 2; ++ni) {
                    acc[mi][ni] = __builtin_amdgcn_mfma_f32_16x16x32_bf16(aH[mi], bH[ni], acc[mi][ni], 0, 0, 0);
                    acc[mi][ni] = __builtin_amdgcn_mfma_f32_16x16x32_bf16(aH[mi], bL[ni], acc[mi][ni], 0, 0, 0);
                    acc[mi][ni] = __builtin_amdgcn_mfma_f32_16x16x32_bf16(aL[mi], bH[ni], acc[mi][ni], 0, 0, 0);
                }
        }
        __syncthreads();
    }
    #pragma unroll
    for (int ni = 0; ni < 2; ++ni) {
        int col = n0 + cg * 32 + ni * 16 + frow;
        float uv = u[col];
        #pragma unroll
        for (int mi = 0; mi < 4; ++mi) {
            int rbase = m0 + rg * 64 + mi * 16 + (lane >> 4) * 4;
            #pragma unroll
            for (int e = 0; e < 4; ++e) {
                float v = acc[mi][ni][e] + uv;
                u16 hi = f2bf(v);
                zh[(size_t)(rbase + e) * 512 + col] = hi;
                zl[(size_t)(rbase + e) * 512 + col] = f2bf(v - bf2f(hi));
            }
        }
    }
}

// ---------------- K4: fused banded attention (reg-staged pipeline) ----------------
// grid 512 = 4b x 128 32-row tiles (XCD-swizzled). block 512 (8 waves).
// Staging pattern per step: [bar][reg->LDS write][bar][issue t+1 global loads][MFMA]
// so global-load latency hides under the compute of the previous step.
__global__ __launch_bounds__(512, 4) void attn_kernel(
    const u16* __restrict__ zh, const u16* __restrict__ zl,
    const u16* __restrict__ xh, const u16* __restrict__ xl,
    const u16* __restrict__ xT, float* __restrict__ out) {
    const int w_ = xcd_swz512((int)blockIdx.x);
    const int b = w_ >> 7, it2 = w_ & 127;
    const int i0 = it2 * 32, j0 = i0 - 128;
    const int mrow0 = b * S_LEN + i0;

    __shared__ __align__(16) u16 smem[36864];       // 72 KB
    u16* Kh = smem;                                  // [288*64]
    u16* Kl = smem + 18432;                          // [288*64]
    u16* PL = smem;                                  // [32*320] (aliases Kh)
    u16* VL = smem + 10240;                          // [64*320]
    __shared__ float sred_max[32 * 4], sred_sum[32 * 4];

    const int tid = threadIdx.x, lane = tid & 63, w = tid >> 6;
    const int g = w >> 2, q = w & 3;
    const int frow = lane & 15, fk = (lane >> 4) * 8;
    const int tstart = g + q * 4;
    const int nt = (q == 3) ? 5 : 4;
    const size_t qoff = (size_t)(mrow0 + g * 16 + frow) * 512;

    f32x4 acc[5] = {};

    // ---- phase 1: QK^T over K=512 (8 chunks of 64), reg-staged pipeline ----
    s16x8 kreg[9];
    // per-thread fixed chunk mapping: f = i*512+tid over 4608 = 2 arrays x 2304
    auto kload = [&](int t) {
        const int k0 = t * 64;
        #pragma unroll
        for (int i = 0; i < 9; ++i) {
            int f = i * 512 + tid;
            int idx = (f < 2304) ? f : f - 2304;
            int r = idx >> 3, c = idx & 7;
            int j = min(max(j0 + r, 0), S_LEN - 1);
            const u16* src = (f < 2304 ? xh : xl);
            kreg[i] = *(const s16x8*)(src + (size_t)(b * S_LEN + j) * 512 + k0 + c * 8);
        }
    };
    auto kwrite = [&]() {
        #pragma unroll
        for (int i = 0; i < 9; ++i) {
            int f = i * 512 + tid;
            int idx = (f < 2304) ? f : f - 2304;
            int r = idx >> 3, c = idx & 7;
            u16* dst = (f < 2304 ? Kh : Kl);
            *(s16x8*)&dst[swz64(r, c * 8)] = kreg[i];
        }
    };

    s16x8 zH0c, zH1c, zL0c, zL1c, zH0n, zH1n, zL0n, zL1n;
    kload(0);
    {
        zH0c = *(const s16x8*)(zh + qoff + 0 + fk);
        zH1c = *(const s16x8*)(zh + qoff + 32 + fk);
        zL0c = *(const s16x8*)(zl + qoff + 0 + fk);
        zL1c = *(const s16x8*)(zl + qoff + 32 + fk);
    }

    for (int t = 0; t < 8; ++t) {
        __syncthreads();                 // prev compute done; kreg(t) drained here
        kwrite();
        __syncthreads();                 // K tile visible to all waves
        if (t < 7) {                     // issue next-step loads; they fly under MFMA
            kload(t + 1);
            const int k1 = (t + 1) * 64;
            zH0n = *(const s16x8*)(zh + qoff + k1 + fk);
            zH1n = *(const s16x8*)(zh + qoff + k1 + 32 + fk);
            zL0n = *(const s16x8*)(zl + qoff + k1 + fk);
            zL1n = *(const s16x8*)(zl + qoff + k1 + 32 + fk);
        }
        __builtin_amdgcn_s_setprio(1);
        #pragma unroll
        for (int kk = 0; kk < 2; ++kk) {
            s16x8 aH = kk ? zH1c : zH0c;
            s16x8 aL = kk ? zL1c : zL0c;
            #pragma unroll
            for (int tt = 0; tt < 5; ++tt) {
                if (tt < nt) {
                    int krow = (tstart + tt) * 16 + frow;
                    s16x8 bH = *(const s16x8*)&Kh[swz64(krow, kk * 32 + fk)];
                    s16x8 bL = *(const s16x8*)&Kl[swz64(krow, kk * 32 + fk)];
                    acc[tt] = __builtin_amdgcn_mfma_f32_16x16x32_bf16(aH, bH, acc[tt], 0, 0, 0);
                    acc[tt] = __builtin_amdgcn_mfma_f32_16x16x32_bf16(aH, bL, acc[tt], 0, 0, 0);
                    acc[tt] = __builtin_amdgcn_mfma_f32_16x16x32_bf16(aL, bH, acc[tt], 0, 0, 0);
                }
            }
        }
        __builtin_amdgcn_s_setprio(0);
        zH0c = zH0n; zH1c = zH1n; zL0c = zL0n; zL1c = zL1n;
    }

    // ---- issue PV step-0 V loads now; they fly under the whole softmax ----
    s16x8 vreg[5];
    auto vload = [&](int ds) {
        const int d0 = ds * 64;
        #pragma unroll
        for (int i = 0; i < 5; ++i) {
            int idx = i * 512 + tid;            // 2560 chunks (64 d-rows x 40)
            int dr = idx / 40, c8 = idx - dr * 40;
            int jb = j0 + c8 * 8;
            jb = min(max(jb, 0), S_LEN - 8);    // clamped cols have P==0
            vreg[i] = *(const s16x8*)&xT[(size_t)(b * 512 + d0 + dr) * S_LEN + jb];
        }
    };
    auto vwrite = [&]() {
        #pragma unroll
        for (int i = 0; i < 5; ++i) {
            int idx = i * 512 + tid;
            int dr = idx / 40, c8 = idx - dr * 40;
            *(s16x8*)&VL[swz320(dr, c8 * 8)] = vreg[i];
        }
    };
    vload(0);

    // ---- phase 2: softmax ----
    const int rq = (lane >> 4) * 4;
    #pragma unroll
    for (int e = 0; e < 4; ++e) {
        int r = g * 16 + rq + e;
        float m = NEG_INF_F;
        #pragma unroll
        for (int tt = 0; tt < 5; ++tt) {
            if (tt < nt) {
                int jj = (tstart + tt) * 16 + frow;
                int dj = jj - r, j = j0 + jj;
                if (dj >= 1 && dj <= 255 && j >= 0 && j < S_LEN) m = fmaxf(m, acc[tt][e]);
            }
        }
        #pragma unroll
        for (int d = 1; d < 16; d <<= 1) m = fmaxf(m, __shfl_xor(m, d));
        if (frow == 0) sred_max[r * 4 + q] = m;
    }
    __syncthreads();
    float sh[4];
    #pragma unroll
    for (int e = 0; e < 4; ++e) {
        int r = g * 16 + rq + e;
        float mx = fmaxf(fmaxf(sred_max[r * 4], sred_max[r * 4 + 1]),
                         fmaxf(sred_max[r * 4 + 2], sred_max[r * 4 + 3]));
        float s = 0.f;
        #pragma unroll
        for (int tt = 0; tt < 5; ++tt) {
            float pv = 0.f;
            if (tt < nt) {
                int jj = (tstart + tt) * 16 + frow;
                int dj = jj - r, j = j0 + jj;
                bool valid = (dj >= 1 && dj <= 255 && j >= 0 && j < S_LEN);
                pv = valid ? __expf(acc[tt][e] - mx) : 0.f;
            }
            acc[tt][e] = pv;
            s += pv;
        }
        #pragma unroll
        for (int d = 1; d < 16; d <<= 1) s += __shfl_xor(s, d);
        sh[e] = s;
    }
    if (frow == 0) {
        #pragma unroll
        for (int e = 0; e < 4; ++e) sred_sum[(g * 16 + rq + e) * 4 + q] = sh[e];
    }
    __syncthreads();
    float invv[4];
    #pragma unroll
    for (int e = 0; e < 4; ++e) {
        int r = g * 16 + rq + e;
        invv[e] = 1.f / (sred_sum[r * 4] + sred_sum[r * 4 + 1] +
                         sred_sum[r * 4 + 2] + sred_sum[r * 4 + 3]);
    }
    // write normalized P to LDS (K buffers dead)
    #pragma unroll
    for (int tt = 0; tt < 5; ++tt) {
        if (tt < nt) {
            int t = tstart + tt;
            #pragma unroll
            for (int e = 0; e < 4; ++e) {
                int r = g * 16 + rq + e;
                PL[swz320(r, t * 16 + frow)] = f2bf(acc[tt][e] * invv[e]);
            }
        }
    }
    if (q == 0) {
        int t = (g == 0) ? 17 : 0;
        int r = g * 16 + frow;
        #pragma unroll
        for (int e2 = 0; e2 < 4; ++e2)
            PL[swz320(r, t * 16 + (lane >> 4) * 4 + e2)] = 0;
    }

    // ---- phase 3: PV, reg-staged pipeline over 8 steps of 64 d-rows ----
    for (int ds = 0; ds < 8; ++ds) {
        __syncthreads();                 // PL ready (ds=0) / prev compute done
        vwrite();
        __syncthreads();                 // V tile visible
        if (ds < 7) vload(ds + 1);       // fly under this step's MFMA
        f32x4 po = {};
        __builtin_amdgcn_s_setprio(1);
        #pragma unroll
        for (int jt = 0; jt < 9; ++jt) {
            s16x8 a = *(const s16x8*)&PL[swz320(g * 16 + frow, jt * 32 + fk)];
            s16x8 bv = *(const s16x8*)&VL[swz320(q * 16 + frow, jt * 32 + fk)];
            po = __builtin_amdgcn_mfma_f32_16x16x32_bf16(a, bv, po, 0, 0, 0);
        }
        __builtin_amdgcn_s_setprio(0);
        #pragma unroll
        for (int e = 0; e < 4; ++e) {
            int r = mrow0 + g * 16 + rq + e;
            out[(size_t)r * 512 + ds * 64 + q * 16 + frow] = po[e];
        }
    }
}

extern "C" void kernel_launch(void* const* d_in, const int* in_sizes, int n_in,
                              void* d_out, int out_size, void* d_ws, size_t ws_size,
                              hipStream_t stream) {
    const float* x  = (const float*)d_in[0];
    const float* Wq = (const float*)d_in[1];
    const float* bq = (const float*)d_in[2];
    const float* Wk = (const float*)d_in[3];
    const float* bk = (const float*)d_in[4];
    (void)bk;
    float* out = (float*)d_out;

    u16* xh  = (u16*)d_ws;
    u16* xl  = xh + (size_t)8388608;
    u16* zh  = xl + (size_t)8388608;
    u16* zl  = zh + (size_t)8388608;
    u16* Mth = zl + (size_t)8388608;
    u16* Mtl = Mth + (size_t)262144;
    u16* xT  = Mtl + (size_t)262144;
    float* uv = (float*)(xT + (size_t)8388608);

    hipLaunchKernelGGL(split_xt_kernel, dim3(2048), dim3(256), 0, stream, x, xh, xl, xT);
    hipLaunchKernelGGL(mt_kernel, dim3(64), dim3(256), 0, stream, Wk, Wq, Mth, Mtl);
    hipLaunchKernelGGL(u_kernel, dim3(8), dim3(256), 0, stream, Wk, bq, uv);
    hipLaunchKernelGGL(z_kernel, dim3(512), dim3(512), 0, stream,
                       xh, xl, Mth, Mtl, uv, zh, zl);
    hipLaunchKernelGGL(attn_kernel, dim3(512), dim3(512), 0, stream,
                       zh, zl, xh, xl, xT, out);
}

// Round 10
// 148.571 us; speedup vs baseline: 1.0581x; 1.0581x over previous
//
#include <hip/hip_runtime.h>
#include <hip/hip_bf16.h>

#define S_LEN 4096
#define NEG_INF_F (-1e30f)

typedef __attribute__((ext_vector_type(4))) float f32x4;
typedef __attribute__((ext_vector_type(8))) short s16x8;
typedef unsigned short u16;

static __device__ __forceinline__ u16 f2bf(float f) {
    unsigned u = __builtin_bit_cast(unsigned, f);
    unsigned r = u + 0x7FFFu + ((u >> 16) & 1u);
    return (u16)(r >> 16);
}
static __device__ __forceinline__ float bf2f(u16 h) {
    unsigned u = ((unsigned)h) << 16;
    return __builtin_bit_cast(float, u);
}
static __device__ __forceinline__ void split4(const float4 v, ushort4& hi, ushort4& lo) {
    hi.x = f2bf(v.x); lo.x = f2bf(v.x - bf2f(hi.x));
    hi.y = f2bf(v.y); lo.y = f2bf(v.y - bf2f(hi.y));
    hi.z = f2bf(v.z); lo.z = f2bf(v.z - bf2f(hi.z));
    hi.w = f2bf(v.w); lo.w = f2bf(v.w - bf2f(hi.w));
}
static __device__ __forceinline__ void gl_lds16(const void* g, void* l) {
    __builtin_amdgcn_global_load_lds(
        (const __attribute__((address_space(1))) void*)g,
        (__attribute__((address_space(3))) void*)l, 16, 0, 0);
}
// swizzled u16 offset within a [rows][64 u16] LDS tile
static __device__ __forceinline__ int swz64(int row, int col_u16) {
    return row * 64 + (col_u16 ^ ((row & 7) << 3));
}
// swizzled u16 offset within a [rows][320 u16] LDS tile
static __device__ __forceinline__ int swz320(int row, int col_u16) {
    return row * 320 + (col_u16 ^ ((row & 7) << 3));
}
// XCD-chunked bijective swizzle for nwg=512
static __device__ __forceinline__ int xcd_swz512(int bid) {
    return (bid & 7) * 64 + (bid >> 3);
}

// ---------------- K0: split x -> xh, xl AND xT (fused transpose) ----------------
__global__ __launch_bounds__(256) void split_xt_kernel(
    const float* __restrict__ x, u16* __restrict__ xh, u16* __restrict__ xl,
    u16* __restrict__ xT) {
    const int bid = blockIdx.x;
    const int dt = bid & 7, st = (bid >> 3) & 63, b = bid >> 9;
    const int s0 = st * 64, d0 = dt * 64;
    __shared__ u16 T[64][72];
    const int tid = threadIdx.x;
    #pragma unroll
    for (int i = 0; i < 4; ++i) {
        int idx = i * 256 + tid;
        int r = idx >> 4, c4 = (idx & 15) * 4;
        float4 v = *(const float4*)(x + (size_t)(b * S_LEN + s0 + r) * 512 + d0 + c4);
        ushort4 hi, lo; split4(v, hi, lo);
        *(ushort4*)(xh + (size_t)(b * S_LEN + s0 + r) * 512 + d0 + c4) = hi;
        *(ushort4*)(xl + (size_t)(b * S_LEN + s0 + r) * 512 + d0 + c4) = lo;
        *(ushort4*)&T[r][c4] = hi;
    }
    __syncthreads();
    #pragma unroll
    for (int i = 0; i < 2; ++i) {
        int idx = i * 256 + tid;
        int dr = idx >> 3, sc = idx & 7;
        s16x8 v;
        #pragma unroll
        for (int t = 0; t < 8; ++t) v[t] = (short)T[sc * 8 + t][dr];
        *(s16x8*)&xT[(size_t)(b * 512 + d0 + dr) * S_LEN + s0 + sc * 8] = v;
    }
}

// ---------------- K1: Mt = Wk^T @ Wq ----------------
__global__ __launch_bounds__(256) void mt_kernel(
    const float* __restrict__ Wk, const float* __restrict__ Wq,
    u16* __restrict__ Mth, u16* __restrict__ Mtl) {
    const int bm = blockIdx.x & 7, bn = blockIdx.x >> 3;
    const int m0 = bm * 64, n0 = bn * 64;
    __shared__ __align__(16) u16 Ath[64 * 72], Atl[64 * 72];
    __shared__ __align__(16) u16 Bth[64 * 72], Btl[64 * 72];
    const int tid = threadIdx.x, lane = tid & 63, w = tid >> 6;
    const int frow = lane & 15, fk = (lane >> 4) * 8;
    f32x4 acc[4] = {};

    for (int h0 = 0; h0 < 512; h0 += 64) {
        #pragma unroll
        for (int i = 0; i < 4; ++i) {
            int idx = i * 256 + tid;
            int h = idx >> 4, c4 = (idx & 15) * 4;
            float4 a = *(const float4*)(Wk + (size_t)(h0 + h) * 512 + m0 + c4);
            ushort4 ahi, alo; split4(a, ahi, alo);
            Ath[(c4 + 0) * 72 + h] = ahi.x; Atl[(c4 + 0) * 72 + h] = alo.x;
            Ath[(c4 + 1) * 72 + h] = ahi.y; Atl[(c4 + 1) * 72 + h] = alo.y;
            Ath[(c4 + 2) * 72 + h] = ahi.z; Atl[(c4 + 2) * 72 + h] = alo.z;
            Ath[(c4 + 3) * 72 + h] = ahi.w; Atl[(c4 + 3) * 72 + h] = alo.w;
            float4 b = *(const float4*)(Wq + (size_t)(h0 + h) * 512 + n0 + c4);
            ushort4 bhi, blo; split4(b, bhi, blo);
            Bth[(c4 + 0) * 72 + h] = bhi.x; Btl[(c4 + 0) * 72 + h] = blo.x;
            Bth[(c4 + 1) * 72 + h] = bhi.y; Btl[(c4 + 1) * 72 + h] = blo.y;
            Bth[(c4 + 2) * 72 + h] = bhi.z; Btl[(c4 + 2) * 72 + h] = blo.z;
            Bth[(c4 + 3) * 72 + h] = bhi.w; Btl[(c4 + 3) * 72 + h] = blo.w;
        }
        __syncthreads();
        #pragma unroll
        for (int kk = 0; kk < 2; ++kk) {
            s16x8 aH = *(const s16x8*)&Ath[(w * 16 + frow) * 72 + kk * 32 + fk];
            s16x8 aL = *(const s16x8*)&Atl[(w * 16 + frow) * 72 + kk * 32 + fk];
            #pragma unroll
            for (int ni = 0; ni < 4; ++ni) {
                s16x8 bH = *(const s16x8*)&Bth[(ni * 16 + frow) * 72 + kk * 32 + fk];
                s16x8 bL = *(const s16x8*)&Btl[(ni * 16 + frow) * 72 + kk * 32 + fk];
                acc[ni] = __builtin_amdgcn_mfma_f32_16x16x32_bf16(aH, bH, acc[ni], 0, 0, 0);
                acc[ni] = __builtin_amdgcn_mfma_f32_16x16x32_bf16(aH, bL, acc[ni], 0, 0, 0);
                acc[ni] = __builtin_amdgcn_mfma_f32_16x16x32_bf16(aL, bH, acc[ni], 0, 0, 0);
            }
        }
        __syncthreads();
    }
    #pragma unroll
    for (int ni = 0; ni < 4; ++ni) {
        int d1 = n0 + ni * 16 + frow;
        #pragma unroll
        for (int e = 0; e < 4; ++e) {
            int d2 = m0 + w * 16 + (lane >> 4) * 4 + e;
            float v = acc[ni][e];
            u16 hi = f2bf(v);
            Mth[(size_t)d2 * 512 + d1] = hi;
            Mtl[(size_t)d2 * 512 + d1] = f2bf(v - bf2f(hi));
        }
    }
}

// ---------------- K2: u = Wk^T @ bq ----------------
__global__ __launch_bounds__(256) void u_kernel(
    const float* __restrict__ Wk, const float* __restrict__ bq,
    float* __restrict__ u) {
    __shared__ float red[4][64];
    const int tid = threadIdx.x, c = tid & 63, hg = tid >> 6;
    const int d2 = blockIdx.x * 64 + c;
    float acc = 0.f;
    for (int h = hg; h < 512; h += 4) acc += Wk[(size_t)h * 512 + d2] * bq[h];
    red[hg][c] = acc;
    __syncthreads();
    if (hg == 0) u[d2] = red[0][c] + red[1][c] + red[2][c] + red[3][c];
}

// ---------------- K3: z = x @ Mt^T + u ----------------
__global__ __launch_bounds__(512) void z_kernel(
    const u16* __restrict__ xh, const u16* __restrict__ xl,
    const u16* __restrict__ Mth, const u16* __restrict__ Mtl,
    const float* __restrict__ u, u16* __restrict__ zh, u16* __restrict__ zl) {
    const int w_ = xcd_swz512((int)blockIdx.x);
    const int bm = w_ >> 2, bn = w_ & 3;
    const int m0 = bm * 128, n0 = bn * 128;
    __shared__ __align__(16) u16 Ah[128 * 64], Al[128 * 64];
    __shared__ __align__(16) u16 Bh[128 * 64], Bl[128 * 64];
    const int tid = threadIdx.x, lane = tid & 63, w = tid >> 6;
    const int rg = w >> 2, cg = w & 3;
    const int frow = lane & 15, fk = (lane >> 4) * 8;
    f32x4 acc[4][2] = {};

    for (int k0 = 0; k0 < 512; k0 += 64) {
        #pragma unroll
        for (int i = 0; i < 2; ++i) {
            int idx = i * 512 + tid;
            int r = idx >> 3, c = idx & 7;
            int sc = (c ^ (r & 7)) * 8;
            gl_lds16(xh + (size_t)(m0 + r) * 512 + k0 + sc, &Ah[idx * 8]);
            gl_lds16(xl + (size_t)(m0 + r) * 512 + k0 + sc, &Al[idx * 8]);
            gl_lds16(Mth + (size_t)(n0 + r) * 512 + k0 + sc, &Bh[idx * 8]);
            gl_lds16(Mtl + (size_t)(n0 + r) * 512 + k0 + sc, &Bl[idx * 8]);
        }
        __syncthreads();
        #pragma unroll
        for (int kk = 0; kk < 2; ++kk) {
            s16x8 aH[4], aL[4], bH[2], bL[2];
            #pragma unroll
            for (int mi = 0; mi < 4; ++mi) {
                int row = rg * 64 + mi * 16 + frow;
                aH[mi] = *(const s16x8*)&Ah[swz64(row, kk * 32 + fk)];
                aL[mi] = *(const s16x8*)&Al[swz64(row, kk * 32 + fk)];
            }
            #pragma unroll
            for (int ni = 0; ni < 2; ++ni) {
                int row = cg * 32 + ni * 16 + frow;
                bH[ni] = *(const s16x8*)&Bh[swz64(row, kk * 32 + fk)];
                bL[ni] = *(const s16x8*)&Bl[swz64(row, kk * 32 + fk)];
            }
            #pragma unroll
            for (int mi = 0; mi < 4; ++mi)
                #pragma unroll
                for (int ni = 0; ni < 2; ++ni) {
                    acc[mi][ni] = __builtin_amdgcn_mfma_f32_16x16x32_bf16(aH[mi], bH[ni], acc[mi][ni], 0, 0, 0);
                    acc[mi][ni] = __builtin_amdgcn_mfma_f32_16x16x32_bf16(aH[mi], bL[ni], acc[mi][ni], 0, 0, 0);
                    acc[mi][ni] = __builtin_amdgcn_mfma_f32_16x16x32_bf16(aL[mi], bH[ni], acc[mi][ni], 0, 0, 0);
                }
        }
        __syncthreads();
    }
    #pragma unroll
    for (int ni = 0; ni < 2; ++ni) {
        int col = n0 + cg * 32 + ni * 16 + frow;
        float uv = u[col];
        #pragma unroll
        for (int mi = 0; mi < 4; ++mi) {
            int rbase = m0 + rg * 64 + mi * 16 + (lane >> 4) * 4;
            #pragma unroll
            for (int e = 0; e < 4; ++e) {
                float v = acc[mi][ni][e] + uv;
                u16 hi = f2bf(v);
                zh[(size_t)(rbase + e) * 512 + col] = hi;
                zl[(size_t)(rbase + e) * 512 + col] = f2bf(v - bf2f(hi));
            }
        }
    }
}

// ---------------- K4: fused banded attention (2-pass QK, LDS double-buffer) ----------------
// grid 512 = 4b x 128 32-row tiles (XCD-swizzled). block 512 (8 waves).
// QK^T split into pass1 (xH tiles: zH*K + zL*K) and pass2 (xL tiles: zH*K), so
// only ONE 36KB K-array is live per step -> true double-buffer in 72KB via
// global_load_lds. Per step: stage(t+1,buf^1) -> MFMA(buf) -> one barrier.
__global__ __launch_bounds__(512, 4) void attn_kernel(
    const u16* __restrict__ zh, const u16* __restrict__ zl,
    const u16* __restrict__ xh, const u16* __restrict__ xl,
    const u16* __restrict__ xT, float* __restrict__ out) {
    const int w_ = xcd_swz512((int)blockIdx.x);
    const int b = w_ >> 7, it2 = w_ & 127;
    const int i0 = it2 * 32, j0 = i0 - 128;
    const int mrow0 = b * S_LEN + i0;

    __shared__ __align__(16) u16 smem[36864];       // 72 KB
    u16* PL = smem;                                  // [32*320] = 20 KB
    u16* VL = smem + 10240;                          // [64*320] = 40 KB
    __shared__ float sred_max[32 * 4], sred_sum[32 * 4];

    const int tid = threadIdx.x, lane = tid & 63, w = tid >> 6;
    const int g = w >> 2, q = w & 3;
    const int frow = lane & 15, fk = (lane >> 4) * 8;
    const int tstart = g + q * 4;
    const int nt = (q == 3) ? 5 : 4;
    const size_t qoff = (size_t)(mrow0 + g * 16 + frow) * 512;

    f32x4 acc[5] = {};

    // stage one 288x64 feature-chunk of array `src` into LDS at offset `doff`
    auto stageK = [&](const u16* src, int t, int doff) {
        const int k0 = t * 64;
        #pragma unroll
        for (int i = 0; i < 5; ++i) {
            int idx = i * 512 + tid;                 // 2304 chunks
            if (idx < 2304) {
                int r = idx >> 3, c = idx & 7;
                int sc = (c ^ (r & 7)) * 8;
                int j = min(max(j0 + r, 0), S_LEN - 1);
                gl_lds16(src + (size_t)(b * S_LEN + j) * 512 + k0 + sc,
                         &smem[doff + idx * 8]);
            }
        }
    };

    stageK(xh, 0, 0);
    __syncthreads();

    int cur = 0;
    // ---- pass 1: xH tiles, acc += zH*KH + zL*KH ----
    for (int t = 0; t < 8; ++t) {
        const int coff = cur * 18432;
        const int noff = 18432 - coff;
        if (t < 7) stageK(xh, t + 1, noff);
        else       stageK(xl, 0, noff);              // first pass-2 tile
        const int k0 = t * 64;
        s16x8 zH0 = *(const s16x8*)(zh + qoff + k0 + fk);
        s16x8 zH1 = *(const s16x8*)(zh + qoff + k0 + 32 + fk);
        s16x8 zL0 = *(const s16x8*)(zl + qoff + k0 + fk);
        s16x8 zL1 = *(const s16x8*)(zl + qoff + k0 + 32 + fk);
        __builtin_amdgcn_s_setprio(1);
        #pragma unroll
        for (int kk = 0; kk < 2; ++kk) {
            s16x8 aH = kk ? zH1 : zH0;
            s16x8 aL = kk ? zL1 : zL0;
            #pragma unroll
            for (int tt = 0; tt < 5; ++tt) {
                if (tt < nt) {
                    int krow = (tstart + tt) * 16 + frow;
                    s16x8 bH = *(const s16x8*)&smem[coff + swz64(krow, kk * 32 + fk)];
                    acc[tt] = __builtin_amdgcn_mfma_f32_16x16x32_bf16(aH, bH, acc[tt], 0, 0, 0);
                    acc[tt] = __builtin_amdgcn_mfma_f32_16x16x32_bf16(aL, bH, acc[tt], 0, 0, 0);
                }
            }
        }
        __builtin_amdgcn_s_setprio(0);
        __syncthreads();
        cur ^= 1;
    }
    // ---- pass 2: xL tiles, acc += zH*KL ----
    for (int t = 0; t < 8; ++t) {
        const int coff = cur * 18432;
        const int noff = 18432 - coff;
        if (t < 7) stageK(xl, t + 1, noff);
        const int k0 = t * 64;
        s16x8 zH0 = *(const s16x8*)(zh + qoff + k0 + fk);
        s16x8 zH1 = *(const s16x8*)(zh + qoff + k0 + 32 + fk);
        __builtin_amdgcn_s_setprio(1);
        #pragma unroll
        for (int kk = 0; kk < 2; ++kk) {
            s16x8 aH = kk ? zH1 : zH0;
            #pragma unroll
            for (int tt = 0; tt < 5; ++tt) {
                if (tt < nt) {
                    int krow = (tstart + tt) * 16 + frow;
                    s16x8 bL = *(const s16x8*)&smem[coff + swz64(krow, kk * 32 + fk)];
                    acc[tt] = __builtin_amdgcn_mfma_f32_16x16x32_bf16(aH, bL, acc[tt], 0, 0, 0);
                }
            }
        }
        __builtin_amdgcn_s_setprio(0);
        __syncthreads();
        cur ^= 1;
    }

    // ---- issue PV step-0 V loads; they fly under the whole softmax ----
    s16x8 vreg[5];
    auto vload = [&](int ds) {
        const int d0 = ds * 64;
        #pragma unroll
        for (int i = 0; i < 5; ++i) {
            int idx = i * 512 + tid;                 // 2560 chunks (64 d-rows x 40)
            int dr = idx / 40, c8 = idx - dr * 40;
            int jb = j0 + c8 * 8;
            jb = min(max(jb, 0), S_LEN - 8);         // clamped cols have P==0
            vreg[i] = *(const s16x8*)&xT[(size_t)(b * 512 + d0 + dr) * S_LEN + jb];
        }
    };
    auto vwrite = [&]() {
        #pragma unroll
        for (int i = 0; i < 5; ++i) {
            int idx = i * 512 + tid;
            int dr = idx / 40, c8 = idx - dr * 40;
            *(s16x8*)&VL[swz320(dr, c8 * 8)] = vreg[i];
        }
    };
    vload(0);

    // ---- softmax ----
    const int rq = (lane >> 4) * 4;
    #pragma unroll
    for (int e = 0; e < 4; ++e) {
        int r = g * 16 + rq + e;
        float m = NEG_INF_F;
        #pragma unroll
        for (int tt = 0; tt < 5; ++tt) {
            if (tt < nt) {
                int jj = (tstart + tt) * 16 + frow;
                int dj = jj - r, j = j0 + jj;
                if (dj >= 1 && dj <= 255 && j >= 0 && j < S_LEN) m = fmaxf(m, acc[tt][e]);
            }
        }
        #pragma unroll
        for (int d = 1; d < 16; d <<= 1) m = fmaxf(m, __shfl_xor(m, d));
        if (frow == 0) sred_max[r * 4 + q] = m;
    }
    __syncthreads();
    float sh[4];
    #pragma unroll
    for (int e = 0; e < 4; ++e) {
        int r = g * 16 + rq + e;
        float mx = fmaxf(fmaxf(sred_max[r * 4], sred_max[r * 4 + 1]),
                         fmaxf(sred_max[r * 4 + 2], sred_max[r * 4 + 3]));
        float s = 0.f;
        #pragma unroll
        for (int tt = 0; tt < 5; ++tt) {
            float pv = 0.f;
            if (tt < nt) {
                int jj = (tstart + tt) * 16 + frow;
                int dj = jj - r, j = j0 + jj;
                bool valid = (dj >= 1 && dj <= 255 && j >= 0 && j < S_LEN);
                pv = valid ? __expf(acc[tt][e] - mx) : 0.f;
            }
            acc[tt][e] = pv;
            s += pv;
        }
        #pragma unroll
        for (int d = 1; d < 16; d <<= 1) s += __shfl_xor(s, d);
        sh[e] = s;
    }
    if (frow == 0) {
        #pragma unroll
        for (int e = 0; e < 4; ++e) sred_sum[(g * 16 + rq + e) * 4 + q] = sh[e];
    }
    __syncthreads();
    float invv[4];
    #pragma unroll
    for (int e = 0; e < 4; ++e) {
        int r = g * 16 + rq + e;
        invv[e] = 1.f / (sred_sum[r * 4] + sred_sum[r * 4 + 1] +
                         sred_sum[r * 4 + 2] + sred_sum[r * 4 + 3]);
    }
    // write normalized P to LDS (K buffers dead)
    #pragma unroll
    for (int tt = 0; tt < 5; ++tt) {
        if (tt < nt) {
            int t = tstart + tt;
            #pragma unroll
            for (int e = 0; e < 4; ++e) {
                int r = g * 16 + rq + e;
                PL[swz320(r, t * 16 + frow)] = f2bf(acc[tt][e] * invv[e]);
            }
        }
    }
    if (q == 0) {
        int t = (g == 0) ? 17 : 0;
        int r = g * 16 + frow;
        #pragma unroll
        for (int e2 = 0; e2 < 4; ++e2)
            PL[swz320(r, t * 16 + (lane >> 4) * 4 + e2)] = 0;
    }

    // ---- PV: 8 steps of 64 d-rows, reg-staged V ----
    for (int ds = 0; ds < 8; ++ds) {
        __syncthreads();                 // PL ready (ds=0) / prev step's reads done
        vwrite();
        __syncthreads();                 // V tile visible
        if (ds < 7) vload(ds + 1);       // flies under this step's MFMA
        f32x4 po = {};
        __builtin_amdgcn_s_setprio(1);
        #pragma unroll
        for (int jt = 0; jt < 9; ++jt) {
            s16x8 a = *(const s16x8*)&PL[swz320(g * 16 + frow, jt * 32 + fk)];
            s16x8 bv = *(const s16x8*)&VL[swz320(q * 16 + frow, jt * 32 + fk)];
            po = __builtin_amdgcn_mfma_f32_16x16x32_bf16(a, bv, po, 0, 0, 0);
        }
        __builtin_amdgcn_s_setprio(0);
        #pragma unroll
        for (int e = 0; e < 4; ++e) {
            int r = mrow0 + g * 16 + rq + e;
            out[(size_t)r * 512 + ds * 64 + q * 16 + frow] = po[e];
        }
    }
}

extern "C" void kernel_launch(void* const* d_in, const int* in_sizes, int n_in,
                              void* d_out, int out_size, void* d_ws, size_t ws_size,
                              hipStream_t stream) {
    const float* x  = (const float*)d_in[0];
    const float* Wq = (const float*)d_in[1];
    const float* bq = (const float*)d_in[2];
    const float* Wk = (const float*)d_in[3];
    const float* bk = (const float*)d_in[4];
    (void)bk;
    float* out = (float*)d_out;

    u16* xh  = (u16*)d_ws;
    u16* xl  = xh + (size_t)8388608;
    u16* zh  = xl + (size_t)8388608;
    u16* zl  = zh + (size_t)8388608;
    u16* Mth = zl + (size_t)8388608;
    u16* Mtl = Mth + (size_t)262144;
    u16* xT  = Mtl + (size_t)262144;
    float* uv = (float*)(xT + (size_t)8388608);

    hipLaunchKernelGGL(split_xt_kernel, dim3(2048), dim3(256), 0, stream, x, xh, xl, xT);
    hipLaunchKernelGGL(mt_kernel, dim3(64), dim3(256), 0, stream, Wk, Wq, Mth, Mtl);
    hipLaunchKernelGGL(u_kernel, dim3(8), dim3(256), 0, stream, Wk, bq, uv);
    hipLaunchKernelGGL(z_kernel, dim3(512), dim3(512), 0, stream,
                       xh, xl, Mth, Mtl, uv, zh, zl);
    hipLaunchKernelGGL(attn_kernel, dim3(512), dim3(512), 0, stream,
                       zh, zl, xh, xl, xT, out);
}